// Round 1
// baseline (69.912 us; speedup 1.0000x reference)
//
#include <hip/hip_runtime.h>
#include <stdint.h>

#define N 2048
#define F 128
#define ALPHA 1.0f
#define PREP_BLOCKS 128

typedef __bf16 bf16x8 __attribute__((ext_vector_type(8)));
typedef float f32x4 __attribute__((ext_vector_type(4)));

// ws layout:
//   [0, 512K)  : Xs        - bf16 X, fragment-major swizzled:
//                element (row,k) -> Xs[(row>>4)*2048 + (k>>3)*128 + (row&15)*8 + (k&7)]
//   then       : nrm[2048]     - row squared norms (of bf16-rounded X)
//   then       : s_final[128]  - global column sums (atomic-accumulated)
//   then       : nsum_final[1] - global sum of row norms (atomic-accumulated)
static constexpr size_t WS_XS  = 0;
static constexpr size_t WS_N   = (size_t)N * F * 2;        // 524288
static constexpr size_t WS_SF  = WS_N + (size_t)N * 4;     // +8192
static constexpr size_t WS_NSF = WS_SF + (size_t)F * 4;    // +512
static constexpr size_t WS_ZERO_BYTES = (size_t)F * 4 + 4; // s_final + nsum_final

// ---------------- prep: fp32 -> bf16 (swizzled), row norms, global col sums --
__global__ __launch_bounds__(256) void gk_prep(const float* __restrict__ X,
                                               ushort* __restrict__ Xs,
                                               float* __restrict__ nrm,
                                               float* __restrict__ s_final,
                                               float* __restrict__ nsum_final) {
    __shared__ float s_lds[F];
    __shared__ float nw_lds[4];
    const int t = threadIdx.x;
    if (t < F) s_lds[t] = 0.f;
    __syncthreads();

    const int r    = t >> 4;        // row within block (16 thr/row)
    const int kidx = t & 15;        // which 8-col chunk
    const int k0   = kidx * 8;
    const int row  = blockIdx.x * 16 + r;

    const float4* px = reinterpret_cast<const float4*>(X + (size_t)row * F + k0);
    float4 v0 = px[0], v1 = px[1];
    float xv[8] = {v0.x, v0.y, v0.z, v0.w, v1.x, v1.y, v1.z, v1.w};

    uint32_t us[8];
    float xb[8];
    float ns = 0.f;
#pragma unroll
    for (int j = 0; j < 8; ++j) {
        uint32_t u = __float_as_uint(xv[j]);
        u = (u + 0x7FFFu + ((u >> 16) & 1u)) >> 16;   // RNE truncate to bf16
        us[j] = u;
        float fb = __uint_as_float(u << 16);
        xb[j] = fb;
        ns += fb * fb;
    }
    uint4 packed;
    packed.x = us[0] | (us[1] << 16);
    packed.y = us[2] | (us[3] << 16);
    packed.z = us[4] | (us[5] << 16);
    packed.w = us[6] | (us[7] << 16);
    // swizzled store: group = row>>4 = blockIdx.x (16 rows/block, aligned)
    *reinterpret_cast<uint4*>(Xs + (size_t)blockIdx.x * 2048 + kidx * 128 + r * 8) = packed;

    // row norm: butterfly over the 16 lanes sharing this row (low 4 bits = kidx)
    float nsr = ns;
#pragma unroll
    for (int off = 1; off < 16; off <<= 1) nsr += __shfl_xor(nsr, off, 64);
    if (kidx == 0) nrm[row] = nsr;
    // continue to full-wave sum (4 rows per wave)
#pragma unroll
    for (int off = 16; off < 64; off <<= 1) nsr += __shfl_xor(nsr, off, 64);
    if ((t & 63) == 0) nw_lds[t >> 6] = nsr;

    // column partials: reduce the 4 rows within this wave (lanes differ by 16,32)
#pragma unroll
    for (int j = 0; j < 8; ++j) {
        float cj = xb[j];
        cj += __shfl_xor(cj, 16, 64);
        cj += __shfl_xor(cj, 32, 64);
        if ((t & 48) == 0) atomicAdd(&s_lds[k0 + j], cj);   // 4 waves -> 4-way
    }
    __syncthreads();

    // global accumulation (device-scope atomics; memset zeroed the targets)
    if (t < F) atomicAdd(&s_final[t], s_lds[t]);
    if (t == 0) atomicAdd(nsum_final, nw_lds[0] + nw_lds[1] + nw_lds[2] + nw_lds[3]);
}

// ---------------- main: C = exp(-(n_i + n_j - 2 X X^T) / (2 sigma^2)) -------
// block = 256 threads (4 waves); block tile 128 rows x 64 cols; wave tile 32x64.
// MFMA operands SWAPPED vs the canonical layout: acc[rg] holds 4 consecutive
// output COLUMNS for a fixed row -> dwordx4 stores. No LDS, no barriers.
__global__ __launch_bounds__(256) void gk_main(const __bf16* __restrict__ Xs,
                                               const float* __restrict__ nrm,
                                               const float* __restrict__ s_final,
                                               const float* __restrict__ nsum_final,
                                               float* __restrict__ out) {
    const int t = threadIdx.x;
    const int wave = t >> 6, lane = t & 63;
    const int quad = lane >> 4, l16 = lane & 15;

    const int row0 = blockIdx.y * 128 + wave * 32;
    const int col0 = blockIdx.x * 64;

    // Fragment loads from swizzled layout: one contiguous 1 KB per wave-load.
    bf16x8 afr[2][4], bfr[4][4];
#pragma unroll
    for (int mi = 0; mi < 2; ++mi) {
        const size_t gbase = (size_t)((row0 + mi * 16) >> 4) * 2048;
#pragma unroll
        for (int kc = 0; kc < 4; ++kc)
            afr[mi][kc] = *reinterpret_cast<const bf16x8*>(
                Xs + gbase + (kc * 4 + quad) * 128 + l16 * 8);
    }
#pragma unroll
    for (int ni = 0; ni < 4; ++ni) {
        const size_t gbase = (size_t)((col0 + ni * 16) >> 4) * 2048;
#pragma unroll
        for (int kc = 0; kc < 4; ++kc)
            bfr[ni][kc] = *reinterpret_cast<const bf16x8*>(
                Xs + gbase + (kc * 4 + quad) * 128 + l16 * 8);
    }

    // Norms for the swapped layout: row i = row0+mi*16+l16 (per lane),
    // col j = col0+ni*16+quad*4+rg (4 consecutive per reg quad).
    float nr[2];
#pragma unroll
    for (int mi = 0; mi < 2; ++mi) nr[mi] = nrm[row0 + mi * 16 + l16];
    f32x4 ncv[4];
#pragma unroll
    for (int ni = 0; ni < 4; ++ni)
        ncv[ni] = *reinterpret_cast<const f32x4*>(nrm + col0 + ni * 16 + quad * 4);

    // Per-lane sigma: 3 coalesced loads + butterfly. No shared, no barrier.
    float c0 = s_final[2 * lane], c1 = s_final[2 * lane + 1];
    float nsum = *nsum_final;
    float v = c0 * c0 + c1 * c1;
#pragma unroll
    for (int off = 32; off; off >>= 1) v += __shfl_xor(v, off, 64);
    const float invn = 1.f / (float)N;
    const float meand2 = 2.f * invn * (nsum - v * invn);
    const float scale = -1.f / (2.f * ALPHA * meand2);

#pragma unroll
    for (int mi = 0; mi < 2; ++mi) {
        float* orow = out + (size_t)(row0 + mi * 16 + l16) * N + col0 + quad * 4;
#pragma unroll
        for (int ni = 0; ni < 4; ++ni) {
            f32x4 acc = {0.f, 0.f, 0.f, 0.f};
#pragma unroll
            for (int kc = 0; kc < 4; ++kc)
                acc = __builtin_amdgcn_mfma_f32_16x16x32_bf16(bfr[ni][kc], afr[mi][kc], acc, 0, 0, 0);
            f32x4 rv;
#pragma unroll
            for (int rg = 0; rg < 4; ++rg) {
                float d2 = fmaxf(nr[mi] + ncv[ni][rg] - 2.f * acc[rg], 0.f);
                rv[rg] = __expf(scale * d2);
            }
            __builtin_nontemporal_store(rv, reinterpret_cast<f32x4*>(orow + ni * 16));
        }
    }
}

extern "C" void kernel_launch(void* const* d_in, const int* in_sizes, int n_in,
                              void* d_out, int out_size, void* d_ws, size_t ws_size,
                              hipStream_t stream) {
    const float* X = (const float*)d_in[0];
    float* out = (float*)d_out;
    char* ws = (char*)d_ws;

    ushort* Xs         = (ushort*)(ws + WS_XS);
    float*  nrm        = (float*)(ws + WS_N);
    float*  s_final    = (float*)(ws + WS_SF);
    float*  nsum_final = (float*)(ws + WS_NSF);

    hipMemsetAsync(ws + WS_SF, 0, WS_ZERO_BYTES, stream);
    gk_prep<<<PREP_BLOCKS, 256, 0, stream>>>(X, Xs, nrm, s_final, nsum_final);

    dim3 grid(N / 64, N / 128);   // x: col tiles (64), y: row tiles (128)
    gk_main<<<grid, 256, 0, stream>>>((const __bf16*)Xs, nrm, s_final, nsum_final, out);
}

// Round 2
// 66.593 us; speedup vs baseline: 1.0498x; 1.0498x over previous
//
#include <hip/hip_runtime.h>
#include <stdint.h>

#define N 2048
#define F 128
#define ALPHA 1.0f
#define PREP_BLOCKS 128

typedef __bf16 bf16x8 __attribute__((ext_vector_type(8)));
typedef float f32x4 __attribute__((ext_vector_type(4)));

// ws layout:
//   [0, 512K)  : Xs        - bf16 X, fragment-major swizzled:
//                element (row,k) -> Xs[(row>>4)*2048 + (k>>3)*128 + (row&15)*8 + (k&7)]
//   then       : nrm[2048]          - row squared norms (of bf16-rounded X)
//   then       : s_part[128][128]   - column sums, K-MAJOR: s_part[k][b]
//   then       : nsum_part[128]     - per-prep-block sum of row norms
static constexpr size_t WS_XS    = 0;
static constexpr size_t WS_N     = (size_t)N * F * 2;                // 524288
static constexpr size_t WS_SP    = WS_N + (size_t)N * 4;             // +8192
static constexpr size_t WS_NSUMP = WS_SP + (size_t)F * PREP_BLOCKS * 4; // +65536

// ---------------- prep: fp32 -> bf16 (swizzled), row norms, column partials --
__global__ __launch_bounds__(256) void gk_prep(const float* __restrict__ X,
                                               ushort* __restrict__ Xs,
                                               float* __restrict__ nrm,
                                               float* __restrict__ s_part,
                                               float* __restrict__ nsum_part) {
    __shared__ float s_lds[F];
    __shared__ float nw_lds[4];
    const int t = threadIdx.x;
    if (t < F) s_lds[t] = 0.f;
    __syncthreads();

    const int r    = t >> 4;        // row within block (16 thr/row)
    const int kidx = t & 15;        // which 8-col chunk
    const int k0   = kidx * 8;
    const int row  = blockIdx.x * 16 + r;

    const float4* px = reinterpret_cast<const float4*>(X + (size_t)row * F + k0);
    float4 v0 = px[0], v1 = px[1];
    float xv[8] = {v0.x, v0.y, v0.z, v0.w, v1.x, v1.y, v1.z, v1.w};

    uint32_t us[8];
    float xb[8];
    float ns = 0.f;
#pragma unroll
    for (int j = 0; j < 8; ++j) {
        uint32_t u = __float_as_uint(xv[j]);
        u = (u + 0x7FFFu + ((u >> 16) & 1u)) >> 16;   // RNE truncate to bf16
        us[j] = u;
        float fb = __uint_as_float(u << 16);
        xb[j] = fb;
        ns += fb * fb;
    }
    uint4 packed;
    packed.x = us[0] | (us[1] << 16);
    packed.y = us[2] | (us[3] << 16);
    packed.z = us[4] | (us[5] << 16);
    packed.w = us[6] | (us[7] << 16);
    // swizzled store: group = row>>4 = blockIdx.x (16 rows/block, aligned)
    *reinterpret_cast<uint4*>(Xs + (size_t)blockIdx.x * 2048 + kidx * 128 + r * 8) = packed;

    // row norm: butterfly over the 16 lanes sharing this row (low 4 bits = kidx)
    float nsr = ns;
#pragma unroll
    for (int off = 1; off < 16; off <<= 1) nsr += __shfl_xor(nsr, off, 64);
    if (kidx == 0) nrm[row] = nsr;
    // continue to full-wave sum (4 rows per wave)
#pragma unroll
    for (int off = 16; off < 64; off <<= 1) nsr += __shfl_xor(nsr, off, 64);
    if ((t & 63) == 0) nw_lds[t >> 6] = nsr;

    // column partials: reduce the 4 rows within this wave (lanes differ by 16,32)
#pragma unroll
    for (int j = 0; j < 8; ++j) {
        float cj = xb[j];
        cj += __shfl_xor(cj, 16, 64);
        cj += __shfl_xor(cj, 32, 64);
        if ((t & 48) == 0) atomicAdd(&s_lds[k0 + j], cj);   // 4 waves -> 4-way LDS
    }
    __syncthreads();

    // k-major partial store: s_part[k][blockIdx.x]
    if (t < F) s_part[(size_t)t * PREP_BLOCKS + blockIdx.x] = s_lds[t];
    if (t == 0) nsum_part[blockIdx.x] = nw_lds[0] + nw_lds[1] + nw_lds[2] + nw_lds[3];
}

// ---------------- main: C = exp(-(n_i + n_j - 2 X X^T) / (2 sigma^2)) -------
// block = 256 threads (4 waves); block tile 128 rows x 64 cols; wave tile 32x64.
// MFMA operands swapped: acc[rg] holds 4 consecutive output COLUMNS of one row
// -> dwordx4 nontemporal stores. One __syncthreads (sigma combine), no atomics.
__global__ __launch_bounds__(256) void gk_main(const __bf16* __restrict__ Xs,
                                               const float* __restrict__ nrm,
                                               const float* __restrict__ s_part,
                                               const float* __restrict__ nsum_part,
                                               float* __restrict__ out) {
    __shared__ float red[8];   // [wave]{v, nsum}
    const int t = threadIdx.x;
    const int wave = t >> 6, lane = t & 63;
    const int quad = lane >> 4, l16 = lane & 15;

    const int row0 = blockIdx.y * 128 + wave * 32;
    const int col0 = blockIdx.x * 64;

    // Fragment loads from swizzled layout: one contiguous 1 KB per wave-load.
    bf16x8 afr[2][4], bfr[4][4];
#pragma unroll
    for (int mi = 0; mi < 2; ++mi) {
        const size_t gbase = (size_t)((row0 + mi * 16) >> 4) * 2048;
#pragma unroll
        for (int kc = 0; kc < 4; ++kc)
            afr[mi][kc] = *reinterpret_cast<const bf16x8*>(
                Xs + gbase + (kc * 4 + quad) * 128 + l16 * 8);
    }
#pragma unroll
    for (int ni = 0; ni < 4; ++ni) {
        const size_t gbase = (size_t)((col0 + ni * 16) >> 4) * 2048;
#pragma unroll
        for (int kc = 0; kc < 4; ++kc)
            bfr[ni][kc] = *reinterpret_cast<const bf16x8*>(
                Xs + gbase + (kc * 4 + quad) * 128 + l16 * 8);
    }

    // Norms for the swapped layout: row i = row0+mi*16+l16 (per lane),
    // col j = col0+ni*16+quad*4+rg (4 consecutive per acc reg).
    float nr[2];
#pragma unroll
    for (int mi = 0; mi < 2; ++mi) nr[mi] = nrm[row0 + mi * 16 + l16];
    f32x4 ncv[4];
#pragma unroll
    for (int ni = 0; ni < 4; ++ni)
        ncv[ni] = *reinterpret_cast<const f32x4*>(nrm + col0 + ni * 16 + quad * 4);

    // Sigma from k-major partials: thread t sums half of k-row (t>>1),
    // 16 contiguous float4 loads (L2-resident; latency hides under frag loads).
    const f32x4* sp = reinterpret_cast<const f32x4*>(
        s_part + (size_t)(t >> 1) * PREP_BLOCKS + (t & 1) * 64);
    f32x4 pa = {0.f, 0.f, 0.f, 0.f};
#pragma unroll
    for (int q = 0; q < 16; ++q) pa += sp[q];
    float sh_half = pa[0] + pa[1] + pa[2] + pa[3];
    float Sk = sh_half + __shfl_xor(sh_half, 1, 64);      // full column sum S_k
    float vv = (t & 1) ? 0.f : Sk * Sk;
    float nsv = (t < PREP_BLOCKS) ? nsum_part[t] : 0.f;
#pragma unroll
    for (int off = 32; off; off >>= 1) {
        vv  += __shfl_xor(vv, off, 64);
        nsv += __shfl_xor(nsv, off, 64);
    }
    if (lane == 0) { red[wave * 2] = vv; red[wave * 2 + 1] = nsv; }
    __syncthreads();
    const float V  = red[0] + red[2] + red[4] + red[6];
    const float NS = red[1] + red[3] + red[5] + red[7];
    const float invn = 1.f / (float)N;
    const float meand2 = 2.f * invn * (NS - V * invn);
    // fold log2(e) into scale; epilogue uses raw v_exp_f32 (exp2)
    const float scale2 = -1.44269504088896f / (2.f * ALPHA * meand2);

#pragma unroll
    for (int mi = 0; mi < 2; ++mi) {
        float* orow = out + (size_t)(row0 + mi * 16 + l16) * N + col0 + quad * 4;
#pragma unroll
        for (int ni = 0; ni < 4; ++ni) {
            f32x4 acc = {0.f, 0.f, 0.f, 0.f};
#pragma unroll
            for (int kc = 0; kc < 4; ++kc)
                acc = __builtin_amdgcn_mfma_f32_16x16x32_bf16(bfr[ni][kc], afr[mi][kc], acc, 0, 0, 0);
            f32x4 rv;
#pragma unroll
            for (int rg = 0; rg < 4; ++rg) {
                float d2 = fmaxf(nr[mi] + ncv[ni][rg] - 2.f * acc[rg], 0.f);
                rv[rg] = __builtin_amdgcn_exp2f(scale2 * d2);
            }
            __builtin_nontemporal_store(rv, reinterpret_cast<f32x4*>(orow + ni * 16));
        }
    }
}

extern "C" void kernel_launch(void* const* d_in, const int* in_sizes, int n_in,
                              void* d_out, int out_size, void* d_ws, size_t ws_size,
                              hipStream_t stream) {
    const float* X = (const float*)d_in[0];
    float* out = (float*)d_out;
    char* ws = (char*)d_ws;

    ushort* Xs      = (ushort*)(ws + WS_XS);
    float*  nrm     = (float*)(ws + WS_N);
    float*  s_part  = (float*)(ws + WS_SP);
    float*  nsum_p  = (float*)(ws + WS_NSUMP);

    gk_prep<<<PREP_BLOCKS, 256, 0, stream>>>(X, Xs, nrm, s_part, nsum_p);

    dim3 grid(N / 64, N / 128);   // x: col tiles (64), y: row tiles (128)
    gk_main<<<grid, 256, 0, stream>>>((const __bf16*)Xs, nrm, s_part, nsum_p, out);
}